// Round 3
// baseline (91.606 us; speedup 1.0000x reference)
//
#include <hip/hip_runtime.h>

// Problem constants (fixed by the reference harness)
#define NF    4
#define NLOC  16384
#define NNEI  128
#define NALL  32768

#define ELEMS_PER_FRAME (NLOC * NNEI)          // 2,097,152
#define Q4_PER_FRAME    (ELEMS_PER_FRAME / 4)  // 524,288 float4 groups
#define THREADS 512
#define BLOCKS_PER_FRAME 256
#define ITERS (Q4_PER_FRAME / (BLOCKS_PER_FRAME * THREADS))  // 4

// ---------------------------------------------------------------------------
// Pre-pass: per extended atom j, compute an 8-bit "column mask":
//   colbits[f][j] bit i  =  (type_mask[i*(ntypes+1) + type_j] != 0)
// Then the main kernel needs only ONE gather per neighbor:
//   mask = (colbits[nl] >> type_i) & 1
// Also writes the padding-atom colbits (type_j = ntypes) at ttab[NF*NALL].
// ---------------------------------------------------------------------------
__global__ void __launch_bounds__(256) build_colbits(
    const int* __restrict__ atype_ext,
    const float* __restrict__ type_mask,
    const int* __restrict__ ntypes_p,
    unsigned char* __restrict__ ttab)
{
    const int t = blockIdx.x * blockDim.x + threadIdx.x;   // 0 .. NF*NALL/4-1
    const int ntypes = ntypes_p[0];
    const int np1 = ntypes + 1;

    const int4 v = reinterpret_cast<const int4*>(atype_ext)[t];
    unsigned bx = 0, by = 0, bz = 0, bw = 0;
    for (int i = 0; i < ntypes; ++i) {
        const float* row = type_mask + i * np1;
        bx |= (row[v.x] != 0.0f ? 1u : 0u) << i;
        by |= (row[v.y] != 0.0f ? 1u : 0u) << i;
        bz |= (row[v.z] != 0.0f ? 1u : 0u) << i;
        bw |= (row[v.w] != 0.0f ? 1u : 0u) << i;
    }
    uchar4 b;
    b.x = (unsigned char)bx; b.y = (unsigned char)by;
    b.z = (unsigned char)bz; b.w = (unsigned char)bw;
    reinterpret_cast<uchar4*>(ttab)[t] = b;

    if (t == 0) {
        unsigned bp = 0;
        for (int i = 0; i < ntypes; ++i)
            bp |= (type_mask[i * np1 + ntypes] != 0.0f ? 1u : 0u) << i;
        ttab[(size_t)NF * NALL] = (unsigned char)bp;   // pad-atom colbits
    }
}

// ---------------------------------------------------------------------------
// Main kernel: stage one frame's 32KB colbits into LDS (+1 pad slot at NALL),
// stream nlist as int4, one LDS byte gather per neighbor, store float4.
// ---------------------------------------------------------------------------
__global__ void __launch_bounds__(THREADS) pair_exclude_mask_kernel(
    const int* __restrict__ nlist,
    const unsigned char* __restrict__ ttab,
    const int* __restrict__ atype_ext,
    float* __restrict__ out)
{
    __shared__ unsigned char stt[NALL + 4];   // [NALL] = pad-atom slot

    const int f = blockIdx.x / BLOCKS_PER_FRAME;
    const int b = blockIdx.x % BLOCKS_PER_FRAME;

    // stage colbits (2048 x uint4 across 512 threads = 4 each)
    {
        const uint4* src = reinterpret_cast<const uint4*>(ttab + (size_t)f * NALL);
        uint4* dst = reinterpret_cast<uint4*>(stt);
        #pragma unroll
        for (int k = 0; k < NALL / 16 / THREADS; ++k)
            dst[threadIdx.x + k * THREADS] = src[threadIdx.x + k * THREADS];
        if (threadIdx.x == 0) stt[NALL] = ttab[(size_t)NF * NALL];
    }
    __syncthreads();

    const int* nl_base = nlist + (size_t)f * ELEMS_PER_FRAME;
    float* out_base = out + (size_t)f * ELEMS_PER_FRAME;
    const int* at_base = atype_ext + (size_t)f * NALL;
    const int q0 = b * (THREADS * ITERS);

    const int qA = q0 + 0 * THREADS + threadIdx.x;
    const int qB = q0 + 1 * THREADS + threadIdx.x;
    const int qC = q0 + 2 * THREADS + threadIdx.x;
    const int qD = q0 + 3 * THREADS + threadIdx.x;

    // issue all global loads up-front: 4 nlist int4 + 4 type_i broadcasts
    const int4 nlA = reinterpret_cast<const int4*>(nl_base)[qA];
    const int4 nlB = reinterpret_cast<const int4*>(nl_base)[qB];
    const int4 nlC = reinterpret_cast<const int4*>(nl_base)[qC];
    const int4 nlD = reinterpret_cast<const int4*>(nl_base)[qD];
    const int tiA = at_base[qA >> 5];   // 32 float4-groups per atom row
    const int tiB = at_base[qB >> 5];
    const int tiC = at_base[qC >> 5];
    const int tiD = at_base[qD >> 5];

#define DO4(nl, ti, q)                                                        \
    {                                                                         \
        const unsigned ix = min((unsigned)nl.x, (unsigned)NALL);              \
        const unsigned iy = min((unsigned)nl.y, (unsigned)NALL);              \
        const unsigned iz = min((unsigned)nl.z, (unsigned)NALL);              \
        const unsigned iw = min((unsigned)nl.w, (unsigned)NALL);              \
        float4 m;                                                             \
        m.x = (float)((stt[ix] >> ti) & 1);                                   \
        m.y = (float)((stt[iy] >> ti) & 1);                                   \
        m.z = (float)((stt[iz] >> ti) & 1);                                   \
        m.w = (float)((stt[iw] >> ti) & 1);                                   \
        reinterpret_cast<float4*>(out_base)[q] = m;                           \
    }

    DO4(nlA, tiA, qA)
    DO4(nlB, tiB, qB)
    DO4(nlC, tiC, qC)
    DO4(nlD, tiD, qD)
#undef DO4
}

extern "C" void kernel_launch(void* const* d_in, const int* in_sizes, int n_in,
                              void* d_out, int out_size, void* d_ws, size_t ws_size,
                              hipStream_t stream) {
    const int*   nlist     = (const int*)d_in[0];
    const int*   atype_ext = (const int*)d_in[1];
    const float* type_mask = (const float*)d_in[2];
    const int*   ntypes_p  = (const int*)d_in[3];
    float*       out       = (float*)d_out;
    unsigned char* ttab    = (unsigned char*)d_ws;   // NF*NALL + 1 bytes

    build_colbits<<<(NF * NALL / 4) / 256, 256, 0, stream>>>(
        atype_ext, type_mask, ntypes_p, ttab);

    pair_exclude_mask_kernel<<<NF * BLOCKS_PER_FRAME, THREADS, 0, stream>>>(
        nlist, ttab, atype_ext, out);
}